// Round 2
// baseline (301.640 us; speedup 1.0000x reference)
//
#include <hip/hip_runtime.h>

// DiceLoss: loss1 = 2 * sum((inp > 0.5) * tgt); loss2 = sum(inp > 0.5) + sum(tgt)
// Memory-bound reduction over 2 x 33.55M fp32 (268 MB read). Roofline ~43 us.

__global__ __launch_bounds__(256) void dice_loss_kernel(
    const float* __restrict__ inp, const float* __restrict__ tgt,
    float* __restrict__ out, long long n4)
{
    const float4* __restrict__ in4 = (const float4*)inp;
    const float4* __restrict__ tg4 = (const float4*)tgt;

    long long idx    = (long long)blockIdx.x * blockDim.x + threadIdx.x;
    long long stride = (long long)gridDim.x * blockDim.x;

    float s_inter = 0.f;  // sum of bin(inp) * tgt
    float s_bin   = 0.f;  // sum of bin(inp)
    float s_tgt   = 0.f;  // sum of tgt

    for (long long i = idx; i < n4; i += stride) {
        float4 a = in4[i];
        float4 b = tg4[i];
        float b0 = (a.x > 0.5f) ? 1.f : 0.f;
        float b1 = (a.y > 0.5f) ? 1.f : 0.f;
        float b2 = (a.z > 0.5f) ? 1.f : 0.f;
        float b3 = (a.w > 0.5f) ? 1.f : 0.f;
        s_bin   += (b0 + b1) + (b2 + b3);
        s_tgt   += (b.x + b.y) + (b.z + b.w);
        s_inter += (b0 * b.x + b1 * b.y) + (b2 * b.z + b3 * b.w);
    }

    // wave-64 shfl_down reduce
    #pragma unroll
    for (int off = 32; off > 0; off >>= 1) {
        s_inter += __shfl_down(s_inter, off, 64);
        s_bin   += __shfl_down(s_bin,   off, 64);
        s_tgt   += __shfl_down(s_tgt,   off, 64);
    }

    __shared__ float red[3][4];
    int wave = threadIdx.x >> 6;
    int lane = threadIdx.x & 63;
    if (lane == 0) {
        red[0][wave] = s_inter;
        red[1][wave] = s_bin;
        red[2][wave] = s_tgt;
    }
    __syncthreads();
    if (threadIdx.x == 0) {
        float ti = (red[0][0] + red[0][1]) + (red[0][2] + red[0][3]);
        float tb = (red[1][0] + red[1][1]) + (red[1][2] + red[1][3]);
        float tt = (red[2][0] + red[2][1]) + (red[2][2] + red[2][3]);
        atomicAdd(&out[0], 2.f * ti);     // loss1
        atomicAdd(&out[1], tb + tt);      // loss2
    }
}

extern "C" void kernel_launch(void* const* d_in, const int* in_sizes, int n_in,
                              void* d_out, int out_size, void* d_ws, size_t ws_size,
                              hipStream_t stream) {
    const float* inp = (const float*)d_in[0];
    const float* tgt = (const float*)d_in[1];
    float* out = (float*)d_out;

    long long n  = (long long)in_sizes[0];   // 33,554,432
    long long n4 = n / 4;                    // divisible (1024*1024 inner)

    // d_out is re-poisoned to 0xAA before every timed launch — zero it.
    hipMemsetAsync(d_out, 0, 2 * sizeof(float), stream);

    const int block = 256;
    const int grid  = 2048;  // memory-bound: cap + grid-stride (G11)
    dice_loss_kernel<<<grid, block, 0, stream>>>(inp, tgt, out, n4);
}

// Round 3
// 288.598 us; speedup vs baseline: 1.0452x; 1.0452x over previous
//
#include <hip/hip_runtime.h>

// DiceLoss: loss1 = 2 * sum((inp > 0.5) * tgt); loss2 = sum(inp > 0.5) + sum(tgt)
// Latency-bound fix (round 2): manual x4 unroll -> 8 independent float4 loads
// in flight per wave. Prior version (VGPR=12, no unroll) serialised on
// vmcnt(0) each iteration -> 128 us despite L3-resident data.

__global__ __launch_bounds__(256) void dice_loss_kernel(
    const float* __restrict__ inp, const float* __restrict__ tgt,
    float* __restrict__ out, long long n4)
{
    const float4* __restrict__ in4 = (const float4*)inp;
    const float4* __restrict__ tg4 = (const float4*)tgt;

    const long long tid  = (long long)blockIdx.x * blockDim.x + threadIdx.x;
    const long long step = (long long)gridDim.x * blockDim.x;

    float s_inter = 0.f;  // sum of bin(inp) * tgt
    float s_bin   = 0.f;  // sum of bin(inp)
    float s_tgt   = 0.f;  // sum of tgt

    long long i = tid;

    // Main unrolled-by-4 loop: issue all 8 loads before consuming any.
    for (; i + 3 * step < n4; i += 4 * step) {
        float4 a0 = in4[i];
        float4 a1 = in4[i +     step];
        float4 a2 = in4[i + 2 * step];
        float4 a3 = in4[i + 3 * step];
        float4 b0 = tg4[i];
        float4 b1 = tg4[i +     step];
        float4 b2 = tg4[i + 2 * step];
        float4 b3 = tg4[i + 3 * step];

        #define ACC(a, b)                                              \
        {                                                              \
            float c0 = (a.x > 0.5f) ? 1.f : 0.f;                       \
            float c1 = (a.y > 0.5f) ? 1.f : 0.f;                       \
            float c2 = (a.z > 0.5f) ? 1.f : 0.f;                       \
            float c3 = (a.w > 0.5f) ? 1.f : 0.f;                       \
            s_bin   += (c0 + c1) + (c2 + c3);                          \
            s_tgt   += (b.x + b.y) + (b.z + b.w);                      \
            s_inter += (c0 * b.x + c1 * b.y) + (c2 * b.z + c3 * b.w);  \
        }
        ACC(a0, b0) ACC(a1, b1) ACC(a2, b2) ACC(a3, b3)
    }

    // Tail (not taken for the 32x1x1024x1024 shape: n4 = 16 * step).
    for (; i < n4; i += step) {
        float4 a = in4[i];
        float4 b = tg4[i];
        ACC(a, b)
    }
    #undef ACC

    // wave-64 shfl_down reduce
    #pragma unroll
    for (int off = 32; off > 0; off >>= 1) {
        s_inter += __shfl_down(s_inter, off, 64);
        s_bin   += __shfl_down(s_bin,   off, 64);
        s_tgt   += __shfl_down(s_tgt,   off, 64);
    }

    __shared__ float red[3][4];
    int wave = threadIdx.x >> 6;
    int lane = threadIdx.x & 63;
    if (lane == 0) {
        red[0][wave] = s_inter;
        red[1][wave] = s_bin;
        red[2][wave] = s_tgt;
    }
    __syncthreads();
    if (threadIdx.x == 0) {
        float ti = (red[0][0] + red[0][1]) + (red[0][2] + red[0][3]);
        float tb = (red[1][0] + red[1][1]) + (red[1][2] + red[1][3]);
        float tt = (red[2][0] + red[2][1]) + (red[2][2] + red[2][3]);
        atomicAdd(&out[0], 2.f * ti);     // loss1
        atomicAdd(&out[1], tb + tt);      // loss2
    }
}

extern "C" void kernel_launch(void* const* d_in, const int* in_sizes, int n_in,
                              void* d_out, int out_size, void* d_ws, size_t ws_size,
                              hipStream_t stream) {
    const float* inp = (const float*)d_in[0];
    const float* tgt = (const float*)d_in[1];
    float* out = (float*)d_out;

    long long n  = (long long)in_sizes[0];   // 33,554,432
    long long n4 = n / 4;                    // divisible (1024*1024 inner)

    // d_out is re-poisoned to 0xAA before every timed launch — zero it.
    hipMemsetAsync(d_out, 0, 2 * sizeof(float), stream);

    const int block = 256;
    const int grid  = 2048;  // 524288 threads -> 16 float4/thread, 4 unrolled iters
    dice_loss_kernel<<<grid, block, 0, stream>>>(inp, tgt, out, n4);
}